// Round 1
// baseline (880.694 us; speedup 1.0000x reference)
//
#include <hip/hip_runtime.h>

#define V_  5
#define LQ  4096
#define C_  256
#define H_  128
#define W_  240
#define HW_ (H_*W_)
#define NH  8
#define DH  32
#define NP  4

// ---------------------------------------------------------------------------
// K1: transpose src0 (V,C,HW) -> src_t (V,HW,C) so bilinear gathers read
// 1 KB contiguous per corner instead of 256 scattered cache lines.
// ---------------------------------------------------------------------------
__global__ __launch_bounds__(256) void k_transpose(const float* __restrict__ src,
                                                   float* __restrict__ dst) {
    __shared__ float tile[32][33];
    int v    = blockIdx.z;
    int pix0 = blockIdx.x * 32;
    int c0   = blockIdx.y * 32;
    int tx = threadIdx.x;   // 0..31
    int ty = threadIdx.y;   // 0..7
    const float* s = src + (size_t)v * C_ * HW_;
    float* d       = dst + (size_t)v * HW_ * C_;
    #pragma unroll
    for (int i = 0; i < 32; i += 8)
        tile[ty + i][tx] = s[(size_t)(c0 + ty + i) * HW_ + pix0 + tx];
    __syncthreads();
    #pragma unroll
    for (int i = 0; i < 32; i += 8)
        d[(size_t)(pix0 + ty + i) * C_ + c0 + tx] = tile[tx][ty + i];
}

// ---------------------------------------------------------------------------
// K2: fused ref_feat gather + so/aw projections + softmax.
// Block = 32 queries of one view. feat kept in LDS, never materialized.
// Outputs: sample coords (x_im,y_im) and softmaxed attention weights.
// ---------------------------------------------------------------------------
__global__ __launch_bounds__(256) void k_feat(
    const float* __restrict__ query, const float* __restrict__ refp,
    const float* __restrict__ src_t,
    const float* __restrict__ W_so, const float* __restrict__ b_so,
    const float* __restrict__ W_aw, const float* __restrict__ b_aw,
    float2* __restrict__ coords, float* __restrict__ aw_out)
{
    __shared__ float feat_s[32][260];
    __shared__ float so_s[32][64];
    __shared__ float aw_s[32][32];

    int t  = threadIdx.x;
    int v  = blockIdx.x >> 7;           // 128 q-tiles per view
    int q0 = (blockIdx.x & 127) << 5;

    // ---- phase A: bilinear ref_feat + query -> feat_s ----
    {
        int ql = t >> 3, sub = t & 7;   // 8 threads per query
        int q = q0 + ql;
        float rx = refp[((size_t)v*LQ + q)*2 + 0];
        float ry = refp[((size_t)v*LQ + q)*2 + 1];
        float gx = fminf(fmaxf(rx*2.f - 1.f, -1.1f), 1.1f);
        float gy = fminf(fmaxf(ry*2.f - 1.f, -1.1f), 1.1f);
        float x = (gx + 1.f) * (W_ * 0.5f) - 0.5f;
        float y = (gy + 1.f) * (H_ * 0.5f) - 0.5f;
        float xf = floorf(x), yf = floorf(y);
        int x0 = (int)xf, y0 = (int)yf;
        float dx = x - xf, dy = y - yf;
        float wgt[4] = {(1.f-dx)*(1.f-dy), dx*(1.f-dy), (1.f-dx)*dy, dx*dy};
        int xs[4] = {x0, x0+1, x0,   x0+1};
        int ys[4] = {y0, y0,   y0+1, y0+1};

        float4 acc[8];
        const float4* qrow = (const float4*)(query + ((size_t)v*LQ + q)*C_);
        #pragma unroll
        for (int j = 0; j < 8; ++j) acc[j] = qrow[j*8 + sub];

        #pragma unroll
        for (int cn = 0; cn < 4; ++cn) {
            int xi = xs[cn], yi = ys[cn];
            if (xi >= 0 && xi < W_ && yi >= 0 && yi < H_) {
                float w = wgt[cn];
                const float4* crow =
                    (const float4*)(src_t + ((size_t)v*HW_ + (size_t)yi*W_ + xi)*C_);
                #pragma unroll
                for (int j = 0; j < 8; ++j) {
                    float4 cv = crow[j*8 + sub];
                    acc[j].x += w*cv.x; acc[j].y += w*cv.y;
                    acc[j].z += w*cv.z; acc[j].w += w*cv.w;
                }
            }
        }
        #pragma unroll
        for (int j = 0; j < 8; ++j) {
            int ch = (j*8 + sub)*4;
            feat_s[ql][ch+0] = acc[j].x; feat_s[ql][ch+1] = acc[j].y;
            feat_s[ql][ch+2] = acc[j].z; feat_s[ql][ch+3] = acc[j].w;
        }
    }
    __syncthreads();

    // ---- phase B: so (64 cols) + aw (32 cols) projections ----
    for (int job = t; job < 32*96; job += 256) {
        int jq = job / 96, col = job % 96;
        const float* frow = feat_s[jq];
        if (col < 64) {
            float s = b_so[col];
            #pragma unroll 4
            for (int k = 0; k < C_; ++k) s += frow[k] * W_so[k*64 + col];
            so_s[jq][col] = s;
        } else {
            int ca = col - 64;
            float s = b_aw[ca];
            #pragma unroll 4
            for (int k = 0; k < C_; ++k) s += frow[k] * W_aw[k*32 + ca];
            aw_s[jq][ca] = s;
        }
    }
    __syncthreads();

    // ---- phase C: softmax over P=4 per head + emit coords ----
    {
        int jq = t >> 3, h = t & 7;     // 32 q x 8 h = 256
        int qq = q0 + jq;
        float rx = refp[((size_t)v*LQ + qq)*2 + 0];
        float ry = refp[((size_t)v*LQ + qq)*2 + 1];
        float sc[4], m = -1e30f;
        #pragma unroll
        for (int p = 0; p < 4; ++p) { sc[p] = aw_s[jq][h*4+p]; m = fmaxf(m, sc[p]); }
        float den = 0.f;
        #pragma unroll
        for (int p = 0; p < 4; ++p) { sc[p] = __expf(sc[p]-m); den += sc[p]; }
        float inv = 1.f/den;
        size_t base = ((size_t)v*LQ + qq)*(NH*NP) + h*NP;
        #pragma unroll
        for (int p = 0; p < 4; ++p) {
            aw_out[base + p] = sc[p]*inv;
            float sx = so_s[jq][h*8 + p*2 + 0];
            float sy = so_s[jq][h*8 + p*2 + 1];
            // x_im = ref_x*W + so_x - 0.5 ; y_im = ref_y*H + so_y - 0.5
            coords[base + p] = make_float2(rx*W_ + sx - 0.5f, ry*H_ + sy - 0.5f);
        }
    }
}

// ---------------------------------------------------------------------------
// K3: value GEMM. value[v][pix][n] = sum_c src0[v][c][pix]*W_ray[c][n]
//     + cam[v][pix][0..2]*W_ray[256..258][n] + b_ray[n].
// A is K-major (src0 rows contiguous in pix) -> coalesced tile loads.
// 128x128 tile, BK=8, 8x8 per thread (f32 vector FMA; no f32 MFMA on CDNA4).
// ---------------------------------------------------------------------------
__global__ __launch_bounds__(256) void k_value(
    const float* __restrict__ src0, const float* __restrict__ cam,
    const float* __restrict__ W_ray, const float* __restrict__ b_ray,
    float* __restrict__ value)
{
    __shared__ float As[8][128];
    __shared__ float Bs[8][128];
    int t = threadIdx.x;
    int mtile = blockIdx.x;              // 0..1199 (240 per view)
    int n0 = blockIdx.y * 128;
    int v    = mtile / 240;
    int pix0 = (mtile % 240) * 128;
    const float* A = src0 + (size_t)v * C_ * HW_;

    int ty = t >> 4, tx = t & 15;
    int lrow = t >> 5, lx4 = (t & 31) * 4;
    float acc[8][8] = {};

    for (int k0 = 0; k0 < 256; k0 += 8) {
        *(float4*)&As[lrow][lx4] = *(const float4*)&A[(size_t)(k0+lrow)*HW_ + pix0 + lx4];
        *(float4*)&Bs[lrow][lx4] = *(const float4*)&W_ray[(size_t)(k0+lrow)*C_ + n0 + lx4];
        __syncthreads();
        #pragma unroll
        for (int kk = 0; kk < 8; ++kk) {
            float a[8], b[8];
            *(float4*)&a[0] = *(const float4*)&As[kk][ty*8];
            *(float4*)&a[4] = *(const float4*)&As[kk][ty*8+4];
            *(float4*)&b[0] = *(const float4*)&Bs[kk][tx*8];
            *(float4*)&b[4] = *(const float4*)&Bs[kk][tx*8+4];
            #pragma unroll
            for (int i = 0; i < 8; ++i)
                #pragma unroll
                for (int j = 0; j < 8; ++j)
                    acc[i][j] += a[i]*b[j];
        }
        __syncthreads();
    }

    // epilogue: camera-ray contribution (k=256..258) + bias
    float wr[3][8], bb[8];
    #pragma unroll
    for (int j3 = 0; j3 < 3; ++j3)
        #pragma unroll
        for (int j = 0; j < 8; ++j)
            wr[j3][j] = W_ray[(size_t)(256+j3)*C_ + n0 + tx*8 + j];
    #pragma unroll
    for (int j = 0; j < 8; ++j) bb[j] = b_ray[n0 + tx*8 + j];

    #pragma unroll
    for (int i = 0; i < 8; ++i) {
        int pix = pix0 + ty*8 + i;
        const float* cp = cam + ((size_t)v*HW_ + pix)*3;
        float c0v = cp[0], c1v = cp[1], c2v = cp[2];
        float ov[8];
        #pragma unroll
        for (int j = 0; j < 8; ++j)
            ov[j] = acc[i][j] + bb[j] + c0v*wr[0][j] + c1v*wr[1][j] + c2v*wr[2][j];
        float* orow = value + ((size_t)v*HW_ + pix)*C_ + n0 + tx*8;
        *(float4*)&orow[0] = make_float4(ov[0],ov[1],ov[2],ov[3]);
        *(float4*)&orow[4] = make_float4(ov[4],ov[5],ov[6],ov[7]);
    }
}

// ---------------------------------------------------------------------------
// K4: deformable sampling + weighted sum over P.
// value layout (V,HW,C): one (pixel,head) slice = 32 contiguous floats (128B)
// -> each 32-lane head-group reads coalesced 128B per corner.
// ---------------------------------------------------------------------------
__global__ __launch_bounds__(256) void k_sample(
    const float* __restrict__ value, const float2* __restrict__ coords,
    const float* __restrict__ aw, float* __restrict__ attn)
{
    int t = threadIdx.x;
    int h = t >> 5;      // 0..7
    int d = t & 31;      // 0..31
    int vq0 = blockIdx.x * 4;
    #pragma unroll
    for (int ql = 0; ql < 4; ++ql) {
        int vq = vq0 + ql;
        int v = vq >> 12;                    // / LQ
        size_t cbase = (size_t)vq * (NH*NP) + h*NP;
        const float* vb = value + (size_t)v*HW_*C_ + h*DH + d;
        float o = 0.f;
        #pragma unroll
        for (int p = 0; p < 4; ++p) {
            float2 cc = coords[cbase + p];
            float a   = aw[cbase + p];
            float xf = floorf(cc.x), yf = floorf(cc.y);
            int x0 = (int)xf, y0 = (int)yf;
            float dx = cc.x - xf, dy = cc.y - yf;
            bool xv0 = (x0 >= 0) & (x0 < W_);
            bool xv1 = (x0 >= -1) & (x0 < W_-1);
            bool yv0 = (y0 >= 0) & (y0 < H_);
            bool yv1 = (y0 >= -1) & (y0 < H_-1);
            float s = 0.f;
            if (yv0 & xv0) s += (1.f-dx)*(1.f-dy) * vb[(size_t)(y0*W_ + x0)*C_];
            if (yv0 & xv1) s += dx*(1.f-dy)       * vb[(size_t)(y0*W_ + x0+1)*C_];
            if (yv1 & xv0) s += (1.f-dx)*dy       * vb[(size_t)((y0+1)*W_ + x0)*C_];
            if (yv1 & xv1) s += dx*dy             * vb[(size_t)((y0+1)*W_ + x0+1)*C_];
            o += a * s;
        }
        attn[(size_t)vq*C_ + h*DH + d] = o;
    }
}

// ---------------------------------------------------------------------------
// K5: output GEMM. out = attn(20480x256) @ W_out(256x256) + b_out.
// 128x128 tile, BK=32, 8x8 per thread. A staged transposed in LDS.
// ---------------------------------------------------------------------------
__global__ __launch_bounds__(256) void k_out(
    const float* __restrict__ attn, const float* __restrict__ W_out,
    const float* __restrict__ b_out, float* __restrict__ out)
{
    __shared__ float As[32][128];
    __shared__ float Bs[32][128];
    int t = threadIdx.x;
    int m0 = blockIdx.x * 128;
    int n0 = blockIdx.y * 128;
    int ty = t >> 4, tx = t & 15;
    int am = t >> 1, akq = (t & 1) * 16;
    int brow = t >> 3, bc = t & 7;
    float acc[8][8] = {};

    for (int k0 = 0; k0 < 256; k0 += 32) {
        float4 av[4];
        #pragma unroll
        for (int j = 0; j < 4; ++j)
            av[j] = *(const float4*)&attn[(size_t)(m0+am)*C_ + k0 + akq + j*4];
        #pragma unroll
        for (int j = 0; j < 4; ++j) {
            As[akq+j*4+0][am] = av[j].x;
            As[akq+j*4+1][am] = av[j].y;
            As[akq+j*4+2][am] = av[j].z;
            As[akq+j*4+3][am] = av[j].w;
        }
        #pragma unroll
        for (int j = 0; j < 4; ++j)
            *(float4*)&Bs[brow][(bc+j*8)*4] =
                *(const float4*)&W_out[(size_t)(k0+brow)*C_ + n0 + (bc+j*8)*4];
        __syncthreads();
        #pragma unroll
        for (int kk = 0; kk < 32; ++kk) {
            float a[8], b[8];
            *(float4*)&a[0] = *(const float4*)&As[kk][ty*8];
            *(float4*)&a[4] = *(const float4*)&As[kk][ty*8+4];
            *(float4*)&b[0] = *(const float4*)&Bs[kk][tx*8];
            *(float4*)&b[4] = *(const float4*)&Bs[kk][tx*8+4];
            #pragma unroll
            for (int i = 0; i < 8; ++i)
                #pragma unroll
                for (int j = 0; j < 8; ++j)
                    acc[i][j] += a[i]*b[j];
        }
        __syncthreads();
    }

    float bb[8];
    #pragma unroll
    for (int j = 0; j < 8; ++j) bb[j] = b_out[n0 + tx*8 + j];
    #pragma unroll
    for (int i = 0; i < 8; ++i) {
        float* orow = out + (size_t)(m0 + ty*8 + i)*C_ + n0 + tx*8;
        *(float4*)&orow[0] = make_float4(acc[i][0]+bb[0], acc[i][1]+bb[1],
                                         acc[i][2]+bb[2], acc[i][3]+bb[3]);
        *(float4*)&orow[4] = make_float4(acc[i][4]+bb[4], acc[i][5]+bb[5],
                                         acc[i][6]+bb[6], acc[i][7]+bb[7]);
    }
}

// ---------------------------------------------------------------------------
extern "C" void kernel_launch(void* const* d_in, const int* in_sizes, int n_in,
                              void* d_out, int out_size, void* d_ws, size_t ws_size,
                              hipStream_t stream)
{
    (void)in_sizes; (void)n_in; (void)out_size; (void)ws_size;
    const float* query = (const float*)d_in[0];
    const float* refp  = (const float*)d_in[1];
    const float* src0  = (const float*)d_in[2];
    const float* cam   = (const float*)d_in[3];
    const float* W_ray = (const float*)d_in[6];
    const float* b_ray = (const float*)d_in[7];
    const float* W_so  = (const float*)d_in[8];
    const float* b_so  = (const float*)d_in[9];
    const float* W_aw  = (const float*)d_in[10];
    const float* b_aw  = (const float*)d_in[11];
    const float* W_out = (const float*)d_in[12];
    const float* b_out = (const float*)d_in[13];
    float* out = (float*)d_out;

    // ws layout (bytes):
    //   buf0   @ 0         : 157,286,400  (src_t, later overwritten by value)
    //   coords @ 157286400 :   5,242,880
    //   aw     @ 162529280 :   2,621,440
    //   attn   @ 165150720 :  20,971,520   -> total 186,122,240
    char* ws = (char*)d_ws;
    float*  buf0   = (float*)(ws);
    float2* coords = (float2*)(ws + 157286400);
    float*  awbuf  = (float*)(ws + 162529280);
    float*  attn   = (float*)(ws + 165150720);

    // K1: transpose src0 -> src_t (buf0)
    k_transpose<<<dim3(HW_/32, C_/32, V_), dim3(32,8), 0, stream>>>(src0, buf0);
    // K2: fused ref_feat + so/aw + softmax -> coords, aw
    k_feat<<<dim3(V_*(LQ/32)), 256, 0, stream>>>(query, refp, buf0,
                                                 W_so, b_so, W_aw, b_aw,
                                                 coords, awbuf);
    // K3: value GEMM (overwrites buf0; safe — K2 already consumed src_t)
    k_value<<<dim3((V_*HW_)/128, 2), 256, 0, stream>>>(src0, cam, W_ray, b_ray, buf0);
    // K4: deformable sampling
    k_sample<<<dim3(V_*LQ/4), 256, 0, stream>>>(buf0, coords, awbuf, attn);
    // K5: output projection
    k_out<<<dim3(V_*LQ/128, 2), 256, 0, stream>>>(attn, W_out, b_out, out);
}

// Round 6
// 628.185 us; speedup vs baseline: 1.4020x; 1.4020x over previous
//
#include <hip/hip_runtime.h>

#define V_  5
#define LQ  4096
#define C_  256
#define H_  128
#define W_  240
#define HW_ (H_*W_)
#define NH  8
#define DH  32
#define NP  4

typedef __attribute__((ext_vector_type(8))) short bf16x8;
typedef __attribute__((ext_vector_type(4))) float f32x4;

// ---- bf16 helpers -----------------------------------------------------------
__device__ __forceinline__ unsigned f2b(float f) {           // f32 -> bf16 bits (RNE)
    unsigned u = __float_as_uint(f);
    return (u + 0x7fffu + ((u >> 16) & 1u)) >> 16;
}
__device__ __forceinline__ unsigned pack2(float a, float b) { // [lo=a, hi=b]
    return f2b(a) | (f2b(b) << 16);
}

// ---------------------------------------------------------------------------
// K0 (prep): build pre-transposed + pre-swizzled bf16 B-images for the two
// MFMA GEMMs. Image layout per K-tile kt (BK=32): for col n, chunk c (=kg),
// the 16B chunk holds W[kt*32+c*8+e][n], e=0..7, at byte
//   kt*16384 + ((n*64 + c*16) ^ ((n&7)<<4))
// which is EXACTLY the LDS image -> GEMM B staging is a linear 16KB copy.
// ---------------------------------------------------------------------------
__global__ __launch_bounds__(256) void k_prep(const float* __restrict__ W_ray,
                                              const float* __restrict__ W_out,
                                              unsigned char* __restrict__ imgR,
                                              unsigned char* __restrict__ imgO)
{
    int g = blockIdx.x * 256 + threadIdx.x;     // 0..16383
    int imgid = g >> 13;
    int cid = g & 8191;
    int kt = cid >> 10, rest = cid & 1023;
    int n = rest >> 2, c = rest & 3;
    const float* Wm = imgid ? W_out : W_ray;
    unsigned char* img = imgid ? imgO : imgR;
    int k0 = kt * 32 + c * 8;
    unsigned u0 = pack2(Wm[(size_t)(k0+0)*C_ + n], Wm[(size_t)(k0+1)*C_ + n]);
    unsigned u1 = pack2(Wm[(size_t)(k0+2)*C_ + n], Wm[(size_t)(k0+3)*C_ + n]);
    unsigned u2 = pack2(Wm[(size_t)(k0+4)*C_ + n], Wm[(size_t)(k0+5)*C_ + n]);
    unsigned u3 = pack2(Wm[(size_t)(k0+6)*C_ + n], Wm[(size_t)(k0+7)*C_ + n]);
    *(uint4*)(img + kt*16384 + ((n*64 + c*16) ^ ((n & 7) << 4))) =
        make_uint4(u0, u1, u2, u3);
}

// ---------------------------------------------------------------------------
// K1: transpose src0 (V,C,HW) f32 -> src_t (V,HW,C) bf16.
// ---------------------------------------------------------------------------
__global__ __launch_bounds__(256) void k_transpose(const float* __restrict__ src,
                                                   unsigned short* __restrict__ dst) {
    __shared__ float tile[32][33];
    int v    = blockIdx.z;
    int pix0 = blockIdx.x * 32;
    int c0   = blockIdx.y * 32;
    int tx = threadIdx.x;   // 0..31
    int ty = threadIdx.y;   // 0..7
    const float* s = src + (size_t)v * C_ * HW_;
    unsigned short* d = dst + (size_t)v * HW_ * C_;
    #pragma unroll
    for (int i = 0; i < 32; i += 8)
        tile[ty + i][tx] = s[(size_t)(c0 + ty + i) * HW_ + pix0 + tx];
    __syncthreads();
    #pragma unroll
    for (int i = 0; i < 32; i += 8)
        d[(size_t)(pix0 + ty + i) * C_ + c0 + tx] = (unsigned short)f2b(tile[tx][ty + i]);
}

// ---------------------------------------------------------------------------
// K2: fused ref_feat gather (bf16 src_t) + so/aw projections + softmax.
// ---------------------------------------------------------------------------
__global__ __launch_bounds__(256) void k_feat(
    const float* __restrict__ query, const float* __restrict__ refp,
    const unsigned short* __restrict__ srcT,
    const float* __restrict__ W_so, const float* __restrict__ b_so,
    const float* __restrict__ W_aw, const float* __restrict__ b_aw,
    float2* __restrict__ coords, float* __restrict__ aw_out)
{
    __shared__ float feat_s[32][260];
    __shared__ float so_s[32][64];
    __shared__ float aw_s[32][32];

    int t  = threadIdx.x;
    int v  = blockIdx.x >> 7;
    int q0 = (blockIdx.x & 127) << 5;

    // ---- phase A: bilinear ref_feat + query -> feat_s ----
    {
        int ql = t >> 3, sub = t & 7;   // 8 threads per query, 32 ch each
        int q = q0 + ql;
        float rx = refp[((size_t)v*LQ + q)*2 + 0];
        float ry = refp[((size_t)v*LQ + q)*2 + 1];
        float gx = fminf(fmaxf(rx*2.f - 1.f, -1.1f), 1.1f);
        float gy = fminf(fmaxf(ry*2.f - 1.f, -1.1f), 1.1f);
        float x = (gx + 1.f) * (W_ * 0.5f) - 0.5f;
        float y = (gy + 1.f) * (H_ * 0.5f) - 0.5f;
        float xf = floorf(x), yf = floorf(y);
        int x0 = (int)xf, y0 = (int)yf;
        float dx = x - xf, dy = y - yf;
        float wgt[4] = {(1.f-dx)*(1.f-dy), dx*(1.f-dy), (1.f-dx)*dy, dx*dy};
        int xs[4] = {x0, x0+1, x0,   x0+1};
        int ys[4] = {y0, y0,   y0+1, y0+1};

        float accv[32];
        const float* qr = query + ((size_t)v*LQ + q)*C_ + sub*32;
        #pragma unroll
        for (int w2 = 0; w2 < 8; ++w2) {
            float4 qv = *(const float4*)(qr + w2*4);
            accv[w2*4+0]=qv.x; accv[w2*4+1]=qv.y; accv[w2*4+2]=qv.z; accv[w2*4+3]=qv.w;
        }
        #pragma unroll
        for (int cn = 0; cn < 4; ++cn) {
            int xi = xs[cn], yi = ys[cn];
            if (xi >= 0 && xi < W_ && yi >= 0 && yi < H_) {
                float wq = wgt[cn];
                const uint4* cr = (const uint4*)(srcT +
                    ((size_t)v*HW_ + (size_t)yi*W_ + xi)*C_ + sub*32);
                #pragma unroll
                for (int w2 = 0; w2 < 4; ++w2) {
                    uint4 uv = cr[w2];
                    unsigned uu[4] = {uv.x, uv.y, uv.z, uv.w};
                    #pragma unroll
                    for (int p2 = 0; p2 < 4; ++p2) {
                        accv[w2*8 + p2*2 + 0] += wq * __uint_as_float(uu[p2] << 16);
                        accv[w2*8 + p2*2 + 1] += wq * __uint_as_float(uu[p2] & 0xffff0000u);
                    }
                }
            }
        }
        #pragma unroll
        for (int k2 = 0; k2 < 32; ++k2) feat_s[ql][sub*32 + k2] = accv[k2];
    }
    __syncthreads();

    // ---- phase B: so (64 cols) + aw (32 cols) projections ----
    for (int job = t; job < 32*96; job += 256) {
        int jq = job / 96, col = job % 96;
        const float* frow = feat_s[jq];
        if (col < 64) {
            float s = b_so[col];
            #pragma unroll 4
            for (int k = 0; k < C_; ++k) s += frow[k] * W_so[k*64 + col];
            so_s[jq][col] = s;
        } else {
            int ca = col - 64;
            float s = b_aw[ca];
            #pragma unroll 4
            for (int k = 0; k < C_; ++k) s += frow[k] * W_aw[k*32 + ca];
            aw_s[jq][ca] = s;
        }
    }
    __syncthreads();

    // ---- phase C: softmax over P=4 per head + emit coords ----
    {
        int jq = t >> 3, h = t & 7;
        int qq = q0 + jq;
        float rx = refp[((size_t)v*LQ + qq)*2 + 0];
        float ry = refp[((size_t)v*LQ + qq)*2 + 1];
        float sc[4], m = -1e30f;
        #pragma unroll
        for (int p = 0; p < 4; ++p) { sc[p] = aw_s[jq][h*4+p]; m = fmaxf(m, sc[p]); }
        float den = 0.f;
        #pragma unroll
        for (int p = 0; p < 4; ++p) { sc[p] = __expf(sc[p]-m); den += sc[p]; }
        float inv = 1.f/den;
        size_t base = ((size_t)v*LQ + qq)*(NH*NP) + h*NP;
        #pragma unroll
        for (int p = 0; p < 4; ++p) {
            aw_out[base + p] = sc[p]*inv;
            float sx = so_s[jq][h*8 + p*2 + 0];
            float sy = so_s[jq][h*8 + p*2 + 1];
            coords[base + p] = make_float2(rx*W_ + sx - 0.5f, ry*H_ + sy - 0.5f);
        }
    }
}

// ---------------------------------------------------------------------------
// K3: value GEMM via bf16 MFMA (builtin intrinsic; compiler handles hazards).
// value[m][n] = sum_c src0[c][m]*W_ray[c][n] + cam epilogue. BM=64 x BN=256,
// BK=32, 4 waves (wave n = wid*64). A reg-staged (f32->bf16 cvt) into
// XOR-swizzled LDS; B is a linear copy of the pre-swizzled image.
// Double-buffered, loads issued before MFMA (T14 issue-early/write-late).
// ---------------------------------------------------------------------------
__global__ __launch_bounds__(256, 3) void k_value(
    const float* __restrict__ src0, const float* __restrict__ cam,
    const float* __restrict__ W_ray, const float* __restrict__ b_ray,
    const unsigned char* __restrict__ imgB,
    unsigned short* __restrict__ value)
{
    __shared__ __align__(16) char As[2][4096];    // 64 rows x 64B (32 bf16)
    __shared__ __align__(16) char Bs[2][16384];   // 256 rows x 64B

    int t = threadIdx.x;
    int wid = t >> 6, lane = t & 63;
    int mtile = blockIdx.x;                 // 0..2399
    int v   = mtile / 480;
    int pl0 = (mtile % 480) * 64;
    const float* A = src0 + (size_t)v * C_ * HW_;

    int sm = t & 63, skg = t >> 6;          // A staging: row sm, chunk skg
    const float* aptr = A + (size_t)(skg*8)*HW_ + pl0 + sm;
    const uint4* bptr = (const uint4*)imgB + t*4;   // 64B per thread per tile

    f32x4 acc[4][4] = {};
    float ar[8]; uint4 br[4];

    // prologue: tile 0
    #pragma unroll
    for (int j = 0; j < 8; ++j) ar[j] = aptr[(size_t)j*HW_];
    #pragma unroll
    for (int j = 0; j < 4; ++j) br[j] = bptr[j];
    {
        uint4 w; w.x=pack2(ar[0],ar[1]); w.y=pack2(ar[2],ar[3]);
                 w.z=pack2(ar[4],ar[5]); w.w=pack2(ar[6],ar[7]);
        *(uint4*)(As[0] + ((sm*64 + skg*16) ^ ((sm & 7) << 4))) = w;
        #pragma unroll
        for (int j = 0; j < 4; ++j) *(uint4*)(Bs[0] + t*64 + j*16) = br[j];
    }
    __syncthreads();

    int nb = wid * 64;
    for (int kt = 0; kt < 8; ++kt) {
        int cur = kt & 1;
        if (kt < 7) {                       // issue next-tile loads early
            const float* ap = aptr + (size_t)((kt+1)*32)*HW_;
            #pragma unroll
            for (int j = 0; j < 8; ++j) ar[j] = ap[(size_t)j*HW_];
            const uint4* bp = bptr + (kt+1)*1024;
            #pragma unroll
            for (int j = 0; j < 4; ++j) br[j] = bp[j];
        }
        bf16x8 af[4], bf[4];
        #pragma unroll
        for (int i = 0; i < 4; ++i) {
            int m = i*16 + (lane & 15);
            af[i] = *(const bf16x8*)(As[cur] + ((m*64 + (lane>>4)*16) ^ ((m & 7) << 4)));
        }
        #pragma unroll
        for (int j = 0; j < 4; ++j) {
            int n = nb + j*16 + (lane & 15);
            bf[j] = *(const bf16x8*)(Bs[cur] + ((n*64 + (lane>>4)*16) ^ ((n & 7) << 4)));
        }
        #pragma unroll
        for (int i = 0; i < 4; ++i)
            #pragma unroll
            for (int j = 0; j < 4; ++j)
                acc[i][j] = __builtin_amdgcn_mfma_f32_16x16x32_bf16(
                                af[i], bf[j], acc[i][j], 0, 0, 0);
        if (kt < 7) {                       // write-late (hidden under MFMA)
            uint4 w; w.x=pack2(ar[0],ar[1]); w.y=pack2(ar[2],ar[3]);
                     w.z=pack2(ar[4],ar[5]); w.w=pack2(ar[6],ar[7]);
            *(uint4*)(As[cur^1] + ((sm*64 + skg*16) ^ ((sm & 7) << 4))) = w;
            #pragma unroll
            for (int j = 0; j < 4; ++j) *(uint4*)(Bs[cur^1] + t*64 + j*16) = br[j];
        }
        __syncthreads();
    }

    // epilogue: bias + camera-ray rows (f32) -> bf16 store
    float wr0[4], wr1[4], wr2[4], bb[4];
    #pragma unroll
    for (int j = 0; j < 4; ++j) {
        int col = nb + j*16 + (lane & 15);
        wr0[j] = W_ray[(size_t)256*C_ + col];
        wr1[j] = W_ray[(size_t)257*C_ + col];
        wr2[j] = W_ray[(size_t)258*C_ + col];
        bb[j]  = b_ray[col];
    }
    #pragma unroll
    for (int i = 0; i < 4; ++i) {
        #pragma unroll
        for (int r = 0; r < 4; ++r) {
            int ml = i*16 + (lane>>4)*4 + r;
            int pix = pl0 + ml;
            const float* cp = cam + ((size_t)v*HW_ + pix)*3;
            float c0v = cp[0], c1v = cp[1], c2v = cp[2];
            size_t rowbase = ((size_t)mtile*64 + ml) * C_;
            #pragma unroll
            for (int j = 0; j < 4; ++j) {
                float o = acc[i][j][r] + bb[j]
                        + c0v*wr0[j] + c1v*wr1[j] + c2v*wr2[j];
                value[rowbase + nb + j*16 + (lane & 15)] = (unsigned short)f2b(o);
            }
        }
    }
}

// ---------------------------------------------------------------------------
// K4: deformable sampling from bf16 value; weighted sum over P; bf16 attn out.
// ---------------------------------------------------------------------------
__global__ __launch_bounds__(256) void k_sample(
    const unsigned short* __restrict__ value, const float2* __restrict__ coords,
    const float* __restrict__ aw, unsigned short* __restrict__ attnb)
{
    int t = threadIdx.x;
    int h = t >> 5;      // 0..7
    int d = t & 31;      // 0..31
    int vq0 = blockIdx.x * 4;
    #pragma unroll
    for (int ql = 0; ql < 4; ++ql) {
        int vq = vq0 + ql;
        int v = vq >> 12;
        size_t cbase = (size_t)vq * (NH*NP) + h*NP;
        const unsigned short* vb = value + (size_t)v*HW_*C_ + h*DH + d;
        float o = 0.f;
        #pragma unroll
        for (int p = 0; p < 4; ++p) {
            float2 cc = coords[cbase + p];
            float a   = aw[cbase + p];
            float xf = floorf(cc.x), yf = floorf(cc.y);
            int x0 = (int)xf, y0 = (int)yf;
            float dx = cc.x - xf, dy = cc.y - yf;
            bool xv0 = (x0 >= 0) & (x0 < W_);
            bool xv1 = (x0 >= -1) & (x0 < W_-1);
            bool yv0 = (y0 >= 0) & (y0 < H_);
            bool yv1 = (y0 >= -1) & (y0 < H_-1);
            float s = 0.f;
            if (yv0 & xv0) s += (1.f-dx)*(1.f-dy) *
                __uint_as_float((unsigned)vb[(size_t)(y0*W_ + x0)*C_] << 16);
            if (yv0 & xv1) s += dx*(1.f-dy) *
                __uint_as_float((unsigned)vb[(size_t)(y0*W_ + x0+1)*C_] << 16);
            if (yv1 & xv0) s += (1.f-dx)*dy *
                __uint_as_float((unsigned)vb[(size_t)((y0+1)*W_ + x0)*C_] << 16);
            if (yv1 & xv1) s += dx*dy *
                __uint_as_float((unsigned)vb[(size_t)((y0+1)*W_ + x0+1)*C_] << 16);
            o += a * s;
        }
        attnb[(size_t)vq*C_ + h*DH + d] = (unsigned short)f2b(o);
    }
}

// ---------------------------------------------------------------------------
// K5: out = attn(bf16) @ W_out + b_out, f32 result. Same MFMA structure.
// ---------------------------------------------------------------------------
__global__ __launch_bounds__(256, 3) void k_out(
    const unsigned short* __restrict__ attnb, const unsigned char* __restrict__ imgB,
    const float* __restrict__ b_out, float* __restrict__ outp)
{
    __shared__ __align__(16) char As[2][4096];
    __shared__ __align__(16) char Bs[2][16384];

    int t = threadIdx.x;
    int wid = t >> 6, lane = t & 63;
    int m0 = blockIdx.x * 64;

    int sm = t >> 2, skg = t & 3;           // A staging: row sm, chunk skg
    const uint4* bptr = (const uint4*)imgB + t*4;

    f32x4 acc[4][4] = {};
    uint4 ar, br[4];

    ar = *(const uint4*)(attnb + (size_t)(m0+sm)*C_ + skg*8);
    #pragma unroll
    for (int j = 0; j < 4; ++j) br[j] = bptr[j];
    *(uint4*)(As[0] + ((sm*64 + skg*16) ^ ((sm & 7) << 4))) = ar;
    #pragma unroll
    for (int j = 0; j < 4; ++j) *(uint4*)(Bs[0] + t*64 + j*16) = br[j];
    __syncthreads();

    int nb = wid * 64;
    for (int kt = 0; kt < 8; ++kt) {
        int cur = kt & 1;
        if (kt < 7) {
            ar = *(const uint4*)(attnb + (size_t)(m0+sm)*C_ + (kt+1)*32 + skg*8);
            const uint4* bp = bptr + (kt+1)*1024;
            #pragma unroll
            for (int j = 0; j < 4; ++j) br[j] = bp[j];
        }
        bf16x8 af[4], bf[4];
        #pragma unroll
        for (int i = 0; i < 4; ++i) {
            int m = i*16 + (lane & 15);
            af[i] = *(const bf16x8*)(As[cur] + ((m*64 + (lane>>4)*16) ^ ((m & 7) << 4)));
        }
        #pragma unroll
        for (int j = 0; j < 4; ++j) {
            int n = nb + j*16 + (lane & 15);
            bf[j] = *(const bf16x8*)(Bs[cur] + ((n*64 + (lane>>4)*16) ^ ((n & 7) << 4)));
        }
        #pragma unroll
        for (int i = 0; i < 4; ++i)
            #pragma unroll
            for (int j = 0; j < 4; ++j)
                acc[i][j] = __builtin_amdgcn_mfma_f32_16x16x32_bf16(
                                af[i], bf[j], acc[i][j], 0, 0, 0);
        if (kt < 7) {
            *(uint4*)(As[cur^1] + ((sm*64 + skg*16) ^ ((sm & 7) << 4))) = ar;
            #pragma unroll
            for (int j = 0; j < 4; ++j) *(uint4*)(Bs[cur^1] + t*64 + j*16) = br[j];
        }
        __syncthreads();
    }

    float bb[4];
    #pragma unroll
    for (int j = 0; j < 4; ++j) bb[j] = b_out[nb + j*16 + (lane & 15)];
    #pragma unroll
    for (int i = 0; i < 4; ++i) {
        #pragma unroll
        for (int r = 0; r < 4; ++r) {
            int ml = i*16 + (lane>>4)*4 + r;
            size_t rowbase = (size_t)(m0 + ml) * C_;
            #pragma unroll
            for (int j = 0; j < 4; ++j)
                outp[rowbase + nb + j*16 + (lane & 15)] = acc[i][j][r] + bb[j];
        }
    }
}

// ---------------------------------------------------------------------------
extern "C" void kernel_launch(void* const* d_in, const int* in_sizes, int n_in,
                              void* d_out, int out_size, void* d_ws, size_t ws_size,
                              hipStream_t stream)
{
    (void)in_sizes; (void)n_in; (void)out_size; (void)ws_size;
    const float* query = (const float*)d_in[0];
    const float* refp  = (const float*)d_in[1];
    const float* src0  = (const float*)d_in[2];
    const float* cam   = (const float*)d_in[3];
    const float* W_ray = (const float*)d_in[6];
    const float* b_ray = (const float*)d_in[7];
    const float* W_so  = (const float*)d_in[8];
    const float* b_so  = (const float*)d_in[9];
    const float* W_aw  = (const float*)d_in[10];
    const float* b_aw  = (const float*)d_in[11];
    const float* W_out = (const float*)d_in[12];
    const float* b_out = (const float*)d_in[13];
    float* out = (float*)d_out;

    // ws layout (bytes):
    //   buf0   @ 0          : 78,643,200  (src_t bf16, later overwritten by value bf16)
    //   imgR   @ 78,643,200 :    131,072
    //   imgO   @ 78,774,272 :    131,072
    //   coords @ 78,905,344 :  5,242,880
    //   aw     @ 84,148,224 :  2,621,440
    //   attnb  @ 86,769,664 : 10,485,760   -> total 97,255,424
    char* ws = (char*)d_ws;
    unsigned short* buf0  = (unsigned short*)(ws);
    unsigned char*  imgR  = (unsigned char*)(ws + 78643200);
    unsigned char*  imgO  = (unsigned char*)(ws + 78774272);
    float2*         coords= (float2*)(ws + 78905344);
    float*          awbuf = (float*)(ws + 84148224);
    unsigned short* attnb = (unsigned short*)(ws + 86769664);

    k_prep<<<dim3(64), 256, 0, stream>>>(W_ray, W_out, imgR, imgO);
    k_transpose<<<dim3(HW_/32, C_/32, V_), dim3(32,8), 0, stream>>>(src0, buf0);
    k_feat<<<dim3(V_*(LQ/32)), 256, 0, stream>>>(query, refp, buf0,
                                                 W_so, b_so, W_aw, b_aw,
                                                 coords, awbuf);
    // overwrites buf0 with value (src_t already consumed by k_feat)
    k_value<<<dim3((V_*HW_)/64), 256, 0, stream>>>(src0, cam, W_ray, b_ray, imgR, buf0);
    k_sample<<<dim3(V_*LQ/4), 256, 0, stream>>>(buf0, coords, awbuf, attnb);
    k_out<<<dim3(V_*LQ/64), 256, 0, stream>>>(attnb, imgO, b_out, out);
}

// Round 10
// 447.231 us; speedup vs baseline: 1.9692x; 1.4046x over previous
//
#include <hip/hip_runtime.h>

#define V_  5
#define LQ  4096
#define C_  256
#define H_  128
#define W_  240
#define HW_ (H_*W_)
#define NH  8
#define DH  32
#define NP  4

typedef __attribute__((ext_vector_type(8))) short bf16x8;
typedef __attribute__((ext_vector_type(4))) float f32x4;

// ---- bf16 helpers -----------------------------------------------------------
__device__ __forceinline__ unsigned f2b(float f) {           // f32 -> bf16 bits (RNE)
    unsigned u = __float_as_uint(f);
    return (u + 0x7fffu + ((u >> 16) & 1u)) >> 16;
}
__device__ __forceinline__ unsigned pack2(float a, float b) { // [lo=a, hi=b]
    return f2b(a) | (f2b(b) << 16);
}

// ---------------------------------------------------------------------------
// K0 (prep): build pre-transposed bf16 B-fragment images.
//  - imgR/imgO (for k_value/k_out): XOR-swizzled LDS images, 16KB per K-tile.
//  - imgF (for k_feat phase B): combined [W_so | W_aw] (N=96), layout
//    [kt][n][c] 16B chunks (chunk c = W[kt*32+c*8+e][n], e=0..7), read
//    directly from L2 as MFMA B-fragments (no swizzle needed for global).
// ---------------------------------------------------------------------------
__global__ __launch_bounds__(256) void k_prep(const float* __restrict__ W_ray,
                                              const float* __restrict__ W_out,
                                              const float* __restrict__ W_so,
                                              const float* __restrict__ W_aw,
                                              unsigned char* __restrict__ imgR,
                                              unsigned char* __restrict__ imgO,
                                              unsigned char* __restrict__ imgF)
{
    int g = blockIdx.x * 256 + threadIdx.x;     // 0..19455
    if (g < 16384) {
        int imgid = g >> 13;
        int cid = g & 8191;
        int kt = cid >> 10, rest = cid & 1023;
        int n = rest >> 2, c = rest & 3;
        const float* Wm = imgid ? W_out : W_ray;
        unsigned char* img = imgid ? imgO : imgR;
        int k0 = kt * 32 + c * 8;
        unsigned u0 = pack2(Wm[(size_t)(k0+0)*C_ + n], Wm[(size_t)(k0+1)*C_ + n]);
        unsigned u1 = pack2(Wm[(size_t)(k0+2)*C_ + n], Wm[(size_t)(k0+3)*C_ + n]);
        unsigned u2 = pack2(Wm[(size_t)(k0+4)*C_ + n], Wm[(size_t)(k0+5)*C_ + n]);
        unsigned u3 = pack2(Wm[(size_t)(k0+6)*C_ + n], Wm[(size_t)(k0+7)*C_ + n]);
        *(uint4*)(img + kt*16384 + ((n*64 + c*16) ^ ((n & 7) << 4))) =
            make_uint4(u0, u1, u2, u3);
    } else {
        int f = g - 16384;                      // 0..3071
        int kt = f / 384;
        int rest = f % 384;
        int n = rest >> 2, c = rest & 3;
        int k0 = kt * 32 + c * 8;
        float w[8];
        #pragma unroll
        for (int e = 0; e < 8; ++e)
            w[e] = (n < 64) ? W_so[(size_t)(k0+e)*64 + n]
                            : W_aw[(size_t)(k0+e)*32 + (n - 64)];
        *(uint4*)(imgF + (size_t)(((kt*96 + n)*4 + c)*16)) =
            make_uint4(pack2(w[0],w[1]), pack2(w[2],w[3]),
                       pack2(w[4],w[5]), pack2(w[6],w[7]));
    }
}

// ---------------------------------------------------------------------------
// K1: transpose src0 (V,C,HW) f32 -> src_t (V,HW,C) bf16.
// ---------------------------------------------------------------------------
__global__ __launch_bounds__(256) void k_transpose(const float* __restrict__ src,
                                                   unsigned short* __restrict__ dst) {
    __shared__ float tile[32][33];
    int v    = blockIdx.z;
    int pix0 = blockIdx.x * 32;
    int c0   = blockIdx.y * 32;
    int tx = threadIdx.x;   // 0..31
    int ty = threadIdx.y;   // 0..7
    const float* s = src + (size_t)v * C_ * HW_;
    unsigned short* d = dst + (size_t)v * HW_ * C_;
    #pragma unroll
    for (int i = 0; i < 32; i += 8)
        tile[ty + i][tx] = s[(size_t)(c0 + ty + i) * HW_ + pix0 + tx];
    __syncthreads();
    #pragma unroll
    for (int i = 0; i < 32; i += 8)
        d[(size_t)(pix0 + ty + i) * C_ + c0 + tx] = (unsigned short)f2b(tile[tx][ty + i]);
}

// ---------------------------------------------------------------------------
// K2: fused ref_feat gather (bf16 src_t) + so/aw projections (MFMA) + softmax.
// Phase A writes feat directly as bf16 MFMA A-fragments (same swizzled layout
// verified by k_value). Phase B: M=32 x N=96 x K=256 via 16x16x32 MFMA,
// 12 tiles over 4 waves; B-fragments read straight from L2 (imgF).
// ---------------------------------------------------------------------------
__global__ __launch_bounds__(256) void k_feat(
    const float* __restrict__ query, const float* __restrict__ refp,
    const unsigned short* __restrict__ srcT,
    const unsigned char* __restrict__ imgF,
    const float* __restrict__ b_so, const float* __restrict__ b_aw,
    float2* __restrict__ coords, float* __restrict__ aw_out)
{
    __shared__ __align__(16) char feat_b[8][2048];   // bf16 A-frag image, 16KB
    __shared__ float so_s[32][66];
    __shared__ float aw_s[32][34];

    int t  = threadIdx.x;
    int wid = t >> 6, lane = t & 63;
    int v  = blockIdx.x >> 7;
    int q0 = (blockIdx.x & 127) << 5;

    // ---- phase A: bilinear ref_feat + query -> feat_b (bf16 fragments) ----
    {
        int ql = t >> 3, sub = t & 7;   // 8 threads per query; sub = K-tile
        int q = q0 + ql;
        float rx = refp[((size_t)v*LQ + q)*2 + 0];
        float ry = refp[((size_t)v*LQ + q)*2 + 1];
        float gx = fminf(fmaxf(rx*2.f - 1.f, -1.1f), 1.1f);
        float gy = fminf(fmaxf(ry*2.f - 1.f, -1.1f), 1.1f);
        float x = (gx + 1.f) * (W_ * 0.5f) - 0.5f;
        float y = (gy + 1.f) * (H_ * 0.5f) - 0.5f;
        float xf = floorf(x), yf = floorf(y);
        int x0 = (int)xf, y0 = (int)yf;
        float dx = x - xf, dy = y - yf;
        float wgt[4] = {(1.f-dx)*(1.f-dy), dx*(1.f-dy), (1.f-dx)*dy, dx*dy};
        int xs[4] = {x0, x0+1, x0,   x0+1};
        int ys[4] = {y0, y0,   y0+1, y0+1};

        float accv[32];
        const float* qr = query + ((size_t)v*LQ + q)*C_ + sub*32;
        #pragma unroll
        for (int w2 = 0; w2 < 8; ++w2) {
            float4 qv = *(const float4*)(qr + w2*4);
            accv[w2*4+0]=qv.x; accv[w2*4+1]=qv.y; accv[w2*4+2]=qv.z; accv[w2*4+3]=qv.w;
        }
        #pragma unroll
        for (int cn = 0; cn < 4; ++cn) {
            int xi = xs[cn], yi = ys[cn];
            if (xi >= 0 && xi < W_ && yi >= 0 && yi < H_) {
                float wq = wgt[cn];
                const uint4* cr = (const uint4*)(srcT +
                    ((size_t)v*HW_ + (size_t)yi*W_ + xi)*C_ + sub*32);
                #pragma unroll
                for (int w2 = 0; w2 < 4; ++w2) {
                    uint4 uv = cr[w2];
                    unsigned uu[4] = {uv.x, uv.y, uv.z, uv.w};
                    #pragma unroll
                    for (int p2 = 0; p2 < 4; ++p2) {
                        accv[w2*8 + p2*2 + 0] += wq * __uint_as_float(uu[p2] << 16);
                        accv[w2*8 + p2*2 + 1] += wq * __uint_as_float(uu[p2] & 0xffff0000u);
                    }
                }
            }
        }
        // write one A-fragment row-tile: row ql, K-tile sub, chunks c2=0..3
        #pragma unroll
        for (int c2 = 0; c2 < 4; ++c2) {
            uint4 w;
            w.x = pack2(accv[c2*8+0], accv[c2*8+1]);
            w.y = pack2(accv[c2*8+2], accv[c2*8+3]);
            w.z = pack2(accv[c2*8+4], accv[c2*8+5]);
            w.w = pack2(accv[c2*8+6], accv[c2*8+7]);
            *(uint4*)(feat_b[sub] + ((ql*64 + c2*16) ^ ((ql & 7) << 4))) = w;
        }
    }
    __syncthreads();

    // ---- phase B: so/aw projections via MFMA (12 tiles, 3 per wave) ----
    #pragma unroll
    for (int jj = 0; jj < 3; ++jj) {
        int j  = wid*3 + jj;
        int mi = j / 6, ni = j % 6;
        f32x4 acc = {};
        #pragma unroll
        for (int kt = 0; kt < 8; ++kt) {
            int row = mi*16 + (lane & 15);
            bf16x8 afr = *(const bf16x8*)(feat_b[kt] +
                          ((row*64 + (lane>>4)*16) ^ ((row & 7) << 4)));
            bf16x8 bfr = *(const bf16x8*)(imgF +
                          (size_t)(((kt*96 + ni*16 + (lane & 15))*4 + (lane>>4))*16));
            acc = __builtin_amdgcn_mfma_f32_16x16x32_bf16(afr, bfr, acc, 0, 0, 0);
        }
        int col = ni*16 + (lane & 15);
        float bias = (col < 64) ? b_so[col] : b_aw[col - 64];
        #pragma unroll
        for (int r = 0; r < 4; ++r) {
            int row = mi*16 + (lane>>4)*4 + r;
            float vv = acc[r] + bias;
            if (col < 64) so_s[row][col] = vv;
            else          aw_s[row][col - 64] = vv;
        }
    }
    __syncthreads();

    // ---- phase C: softmax over P=4 per head + emit coords ----
    {
        int jq = t >> 3, h = t & 7;
        int qq = q0 + jq;
        float rx = refp[((size_t)v*LQ + qq)*2 + 0];
        float ry = refp[((size_t)v*LQ + qq)*2 + 1];
        float sc[4], m = -1e30f;
        #pragma unroll
        for (int p = 0; p < 4; ++p) { sc[p] = aw_s[jq][h*4+p]; m = fmaxf(m, sc[p]); }
        float den = 0.f;
        #pragma unroll
        for (int p = 0; p < 4; ++p) { sc[p] = __expf(sc[p]-m); den += sc[p]; }
        float inv = 1.f/den;
        size_t base = ((size_t)v*LQ + qq)*(NH*NP) + h*NP;
        #pragma unroll
        for (int p = 0; p < 4; ++p) {
            aw_out[base + p] = sc[p]*inv;
            float sx = so_s[jq][h*8 + p*2 + 0];
            float sy = so_s[jq][h*8 + p*2 + 1];
            coords[base + p] = make_float2(rx*W_ + sx - 0.5f, ry*H_ + sy - 0.5f);
        }
    }
}

// ---------------------------------------------------------------------------
// K3: value GEMM via bf16 MFMA. value[m][n] = sum_c src0[c][m]*W_ray[c][n]
// (+cam epilogue in f32). BM=64 x BN=256, BK=32, 4 waves (wave n = wid*64).
// A reg-staged (f32->bf16 cvt) into XOR-swizzled LDS; B is a linear copy of
// the pre-swizzled image. Double-buffered, loads issued before MFMA (T14).
// ---------------------------------------------------------------------------
__global__ __launch_bounds__(256, 3) void k_value(
    const float* __restrict__ src0, const float* __restrict__ cam,
    const float* __restrict__ W_ray, const float* __restrict__ b_ray,
    const unsigned char* __restrict__ imgB,
    unsigned short* __restrict__ value)
{
    __shared__ __align__(16) char As[2][4096];    // 64 rows x 64B (32 bf16)
    __shared__ __align__(16) char Bs[2][16384];   // 256 rows x 64B

    int t = threadIdx.x;
    int wid = t >> 6, lane = t & 63;
    int mtile = blockIdx.x;                 // 0..2399
    int v   = mtile / 480;
    int pl0 = (mtile % 480) * 64;
    const float* A = src0 + (size_t)v * C_ * HW_;

    int sm = t & 63, skg = t >> 6;          // A staging: row sm, chunk skg
    const float* aptr = A + (size_t)(skg*8)*HW_ + pl0 + sm;
    const uint4* bptr = (const uint4*)imgB + t*4;   // 64B per thread per tile

    f32x4 acc[4][4] = {};
    float ar[8]; uint4 br[4];

    // prologue: tile 0
    #pragma unroll
    for (int j = 0; j < 8; ++j) ar[j] = aptr[(size_t)j*HW_];
    #pragma unroll
    for (int j = 0; j < 4; ++j) br[j] = bptr[j];
    {
        uint4 w; w.x=pack2(ar[0],ar[1]); w.y=pack2(ar[2],ar[3]);
                 w.z=pack2(ar[4],ar[5]); w.w=pack2(ar[6],ar[7]);
        *(uint4*)(As[0] + ((sm*64 + skg*16) ^ ((sm & 7) << 4))) = w;
        #pragma unroll
        for (int j = 0; j < 4; ++j) *(uint4*)(Bs[0] + t*64 + j*16) = br[j];
    }
    __syncthreads();

    int nb = wid * 64;
    for (int kt = 0; kt < 8; ++kt) {
        int cur = kt & 1;
        if (kt < 7) {                       // issue next-tile loads early
            const float* ap = aptr + (size_t)((kt+1)*32)*HW_;
            #pragma unroll
            for (int j = 0; j < 8; ++j) ar[j] = ap[(size_t)j*HW_];
            const uint4* bp = bptr + (kt+1)*1024;
            #pragma unroll
            for (int j = 0; j < 4; ++j) br[j] = bp[j];
        }
        bf16x8 af[4], bf[4];
        #pragma unroll
        for (int i = 0; i < 4; ++i) {
            int m = i*16 + (lane & 15);
            af[i] = *(const bf16x8*)(As[cur] + ((m*64 + (lane>>4)*16) ^ ((m & 7) << 4)));
        }
        #pragma unroll
        for (int j = 0; j < 4; ++j) {
            int n = nb + j*16 + (lane & 15);
            bf[j] = *(const bf16x8*)(Bs[cur] + ((n*64 + (lane>>4)*16) ^ ((n & 7) << 4)));
        }
        #pragma unroll
        for (int i = 0; i < 4; ++i)
            #pragma unroll
            for (int j = 0; j < 4; ++j)
                acc[i][j] = __builtin_amdgcn_mfma_f32_16x16x32_bf16(
                                af[i], bf[j], acc[i][j], 0, 0, 0);
        if (kt < 7) {                       // write-late (hidden under MFMA)
            uint4 w; w.x=pack2(ar[0],ar[1]); w.y=pack2(ar[2],ar[3]);
                     w.z=pack2(ar[4],ar[5]); w.w=pack2(ar[6],ar[7]);
            *(uint4*)(As[cur^1] + ((sm*64 + skg*16) ^ ((sm & 7) << 4))) = w;
            #pragma unroll
            for (int j = 0; j < 4; ++j) *(uint4*)(Bs[cur^1] + t*64 + j*16) = br[j];
        }
        __syncthreads();
    }

    // epilogue: bias + camera-ray rows (f32) -> bf16 store
    float wr0[4], wr1[4], wr2[4], bb[4];
    #pragma unroll
    for (int j = 0; j < 4; ++j) {
        int col = nb + j*16 + (lane & 15);
        wr0[j] = W_ray[(size_t)256*C_ + col];
        wr1[j] = W_ray[(size_t)257*C_ + col];
        wr2[j] = W_ray[(size_t)258*C_ + col];
        bb[j]  = b_ray[col];
    }
    #pragma unroll
    for (int i = 0; i < 4; ++i) {
        #pragma unroll
        for (int r = 0; r < 4; ++r) {
            int ml = i*16 + (lane>>4)*4 + r;
            int pix = pl0 + ml;
            const float* cp = cam + ((size_t)v*HW_ + pix)*3;
            float c0v = cp[0], c1v = cp[1], c2v = cp[2];
            size_t rowbase = ((size_t)mtile*64 + ml) * C_;
            #pragma unroll
            for (int j = 0; j < 4; ++j) {
                float o = acc[i][j][r] + bb[j]
                        + c0v*wr0[j] + c1v*wr1[j] + c2v*wr2[j];
                value[rowbase + nb + j*16 + (lane & 15)] = (unsigned short)f2b(o);
            }
        }
    }
}

// ---------------------------------------------------------------------------
// K4: deformable sampling from bf16 value; weighted sum over P; bf16 attn out.
// ---------------------------------------------------------------------------
__global__ __launch_bounds__(256) void k_sample(
    const unsigned short* __restrict__ value, const float2* __restrict__ coords,
    const float* __restrict__ aw, unsigned short* __restrict__ attnb)
{
    int t = threadIdx.x;
    int h = t >> 5;      // 0..7
    int d = t & 31;      // 0..31
    int vq0 = blockIdx.x * 4;
    #pragma unroll
    for (int ql = 0; ql < 4; ++ql) {
        int vq = vq0 + ql;
        int v = vq >> 12;
        size_t cbase = (size_t)vq * (NH*NP) + h*NP;
        const unsigned short* vb = value + (size_t)v*HW_*C_ + h*DH + d;
        float o = 0.f;
        #pragma unroll
        for (int p = 0; p < 4; ++p) {
            float2 cc = coords[cbase + p];
            float a   = aw[cbase + p];
            float xf = floorf(cc.x), yf = floorf(cc.y);
            int x0 = (int)xf, y0 = (int)yf;
            float dx = cc.x - xf, dy = cc.y - yf;
            bool xv0 = (x0 >= 0) & (x0 < W_);
            bool xv1 = (x0 >= -1) & (x0 < W_-1);
            bool yv0 = (y0 >= 0) & (y0 < H_);
            bool yv1 = (y0 >= -1) & (y0 < H_-1);
            float s = 0.f;
            if (yv0 & xv0) s += (1.f-dx)*(1.f-dy) *
                __uint_as_float((unsigned)vb[(size_t)(y0*W_ + x0)*C_] << 16);
            if (yv0 & xv1) s += dx*(1.f-dy) *
                __uint_as_float((unsigned)vb[(size_t)(y0*W_ + x0+1)*C_] << 16);
            if (yv1 & xv0) s += (1.f-dx)*dy *
                __uint_as_float((unsigned)vb[(size_t)((y0+1)*W_ + x0)*C_] << 16);
            if (yv1 & xv1) s += dx*dy *
                __uint_as_float((unsigned)vb[(size_t)((y0+1)*W_ + x0+1)*C_] << 16);
            o += a * s;
        }
        attnb[(size_t)vq*C_ + h*DH + d] = (unsigned short)f2b(o);
    }
}

// ---------------------------------------------------------------------------
// K5: out = attn(bf16) @ W_out + b_out, f32 result. Same MFMA structure.
// ---------------------------------------------------------------------------
__global__ __launch_bounds__(256, 3) void k_out(
    const unsigned short* __restrict__ attnb, const unsigned char* __restrict__ imgB,
    const float* __restrict__ b_out, float* __restrict__ outp)
{
    __shared__ __align__(16) char As[2][4096];
    __shared__ __align__(16) char Bs[2][16384];

    int t = threadIdx.x;
    int wid = t >> 6, lane = t & 63;
    int m0 = blockIdx.x * 64;

    int sm = t >> 2, skg = t & 3;           // A staging: row sm, chunk skg
    const uint4* bptr = (const uint4*)imgB + t*4;

    f32x4 acc[4][4] = {};
    uint4 ar, br[4];

    ar = *(const uint4*)(attnb + (size_t)(m0+sm)*C_ + skg*8);
    #pragma unroll
    for (int j = 0; j < 4; ++j) br[j] = bptr[j];
    *(uint4*)(As[0] + ((sm*64 + skg*16) ^ ((sm & 7) << 4))) = ar;
    #pragma unroll
    for (int j = 0; j < 4; ++j) *(uint4*)(Bs[0] + t*64 + j*16) = br[j];
    __syncthreads();

    int nb = wid * 64;
    for (int kt = 0; kt < 8; ++kt) {
        int cur = kt & 1;
        if (kt < 7) {
            ar = *(const uint4*)(attnb + (size_t)(m0+sm)*C_ + (kt+1)*32 + skg*8);
            const uint4* bp = bptr + (kt+1)*1024;
            #pragma unroll
            for (int j = 0; j < 4; ++j) br[j] = bp[j];
        }
        bf16x8 af[4], bf[4];
        #pragma unroll
        for (int i = 0; i < 4; ++i) {
            int m = i*16 + (lane & 15);
            af[i] = *(const bf16x8*)(As[cur] + ((m*64 + (lane>>4)*16) ^ ((m & 7) << 4)));
        }
        #pragma unroll
        for (int j = 0; j < 4; ++j) {
            int n = nb + j*16 + (lane & 15);
            bf[j] = *(const bf16x8*)(Bs[cur] + ((n*64 + (lane>>4)*16) ^ ((n & 7) << 4)));
        }
        #pragma unroll
        for (int i = 0; i < 4; ++i)
            #pragma unroll
            for (int j = 0; j < 4; ++j)
                acc[i][j] = __builtin_amdgcn_mfma_f32_16x16x32_bf16(
                                af[i], bf[j], acc[i][j], 0, 0, 0);
        if (kt < 7) {
            *(uint4*)(As[cur^1] + ((sm*64 + skg*16) ^ ((sm & 7) << 4))) = ar;
            #pragma unroll
            for (int j = 0; j < 4; ++j) *(uint4*)(Bs[cur^1] + t*64 + j*16) = br[j];
        }
        __syncthreads();
    }

    float bb[4];
    #pragma unroll
    for (int j = 0; j < 4; ++j) bb[j] = b_out[nb + j*16 + (lane & 15)];
    #pragma unroll
    for (int i = 0; i < 4; ++i) {
        #pragma unroll
        for (int r = 0; r < 4; ++r) {
            int ml = i*16 + (lane>>4)*4 + r;
            size_t rowbase = (size_t)(m0 + ml) * C_;
            #pragma unroll
            for (int j = 0; j < 4; ++j)
                outp[rowbase + nb + j*16 + (lane & 15)] = acc[i][j][r] + bb[j];
        }
    }
}

// ---------------------------------------------------------------------------
extern "C" void kernel_launch(void* const* d_in, const int* in_sizes, int n_in,
                              void* d_out, int out_size, void* d_ws, size_t ws_size,
                              hipStream_t stream)
{
    (void)in_sizes; (void)n_in; (void)out_size; (void)ws_size;
    const float* query = (const float*)d_in[0];
    const float* refp  = (const float*)d_in[1];
    const float* src0  = (const float*)d_in[2];
    const float* cam   = (const float*)d_in[3];
    const float* W_ray = (const float*)d_in[6];
    const float* b_ray = (const float*)d_in[7];
    const float* W_so  = (const float*)d_in[8];
    const float* b_so  = (const float*)d_in[9];
    const float* W_aw  = (const float*)d_in[10];
    const float* b_aw  = (const float*)d_in[11];
    const float* W_out = (const float*)d_in[12];
    const float* b_out = (const float*)d_in[13];
    float* out = (float*)d_out;

    // ws layout (bytes):
    //   buf0   @ 0          : 78,643,200  (src_t bf16, later overwritten by value bf16)
    //   imgR   @ 78,643,200 :    131,072
    //   imgO   @ 78,774,272 :    131,072
    //   imgF   @ 78,905,344 :     49,152
    //   coords @ 78,954,496 :  5,242,880
    //   aw     @ 84,197,376 :  2,621,440
    //   attnb  @ 86,818,816 : 10,485,760   -> total 97,304,576
    char* ws = (char*)d_ws;
    unsigned short* buf0  = (unsigned short*)(ws);
    unsigned char*  imgR  = (unsigned char*)(ws + 78643200);
    unsigned char*  imgO  = (unsigned char*)(ws + 78774272);
    unsigned char*  imgF  = (unsigned char*)(ws + 78905344);
    float2*         coords= (float2*)(ws + 78954496);
    float*          awbuf = (float*)(ws + 84197376);
    unsigned short* attnb = (unsigned short*)(ws + 86818816);

    k_prep<<<dim3(76), 256, 0, stream>>>(W_ray, W_out, W_so, W_aw, imgR, imgO, imgF);
    k_transpose<<<dim3(HW_/32, C_/32, V_), dim3(32,8), 0, stream>>>(src0, buf0);
    k_feat<<<dim3(V_*(LQ/32)), 256, 0, stream>>>(query, refp, buf0, imgF,
                                                 b_so, b_aw, coords, awbuf);
    // overwrites buf0 with value (src_t already consumed by k_feat)
    k_value<<<dim3((V_*HW_)/64), 256, 0, stream>>>(src0, cam, W_ray, b_ray, imgR, buf0);
    k_sample<<<dim3(V_*LQ/4), 256, 0, stream>>>(buf0, coords, awbuf, attnb);
    k_out<<<dim3(V_*LQ/64), 256, 0, stream>>>(attnb, imgO, b_out, out);
}

// Round 11
// 429.058 us; speedup vs baseline: 2.0526x; 1.0424x over previous
//
#include <hip/hip_runtime.h>

#define V_  5
#define LQ  4096
#define C_  256
#define H_  128
#define W_  240
#define HW_ (H_*W_)
#define NH  8
#define DH  32
#define NP  4

typedef __attribute__((ext_vector_type(8))) short bf16x8;
typedef __attribute__((ext_vector_type(4))) float f32x4;

// ---- bf16 helpers -----------------------------------------------------------
__device__ __forceinline__ unsigned f2b(float f) {           // f32 -> bf16 bits (RNE)
    unsigned u = __float_as_uint(f);
    return (u + 0x7fffu + ((u >> 16) & 1u)) >> 16;
}
__device__ __forceinline__ unsigned pack2(float a, float b) { // [lo=a, hi=b]
    return f2b(a) | (f2b(b) << 16);
}

// ---------------------------------------------------------------------------
// K0 (prep): build pre-transposed bf16 B-fragment images.
//  - imgR/imgO (for k_value/k_out): XOR-swizzled LDS images, 16KB per K-tile.
//  - imgF (for k_feat phase B): combined [W_so | W_aw] (N=96), layout
//    [kt][n][c] 16B chunks, read directly from L2 as MFMA B-fragments.
// ---------------------------------------------------------------------------
__global__ __launch_bounds__(256) void k_prep(const float* __restrict__ W_ray,
                                              const float* __restrict__ W_out,
                                              const float* __restrict__ W_so,
                                              const float* __restrict__ W_aw,
                                              unsigned char* __restrict__ imgR,
                                              unsigned char* __restrict__ imgO,
                                              unsigned char* __restrict__ imgF)
{
    int g = blockIdx.x * 256 + threadIdx.x;     // 0..19455
    if (g < 16384) {
        int imgid = g >> 13;
        int cid = g & 8191;
        int kt = cid >> 10, rest = cid & 1023;
        int n = rest >> 2, c = rest & 3;
        const float* Wm = imgid ? W_out : W_ray;
        unsigned char* img = imgid ? imgO : imgR;
        int k0 = kt * 32 + c * 8;
        unsigned u0 = pack2(Wm[(size_t)(k0+0)*C_ + n], Wm[(size_t)(k0+1)*C_ + n]);
        unsigned u1 = pack2(Wm[(size_t)(k0+2)*C_ + n], Wm[(size_t)(k0+3)*C_ + n]);
        unsigned u2 = pack2(Wm[(size_t)(k0+4)*C_ + n], Wm[(size_t)(k0+5)*C_ + n]);
        unsigned u3 = pack2(Wm[(size_t)(k0+6)*C_ + n], Wm[(size_t)(k0+7)*C_ + n]);
        *(uint4*)(img + kt*16384 + ((n*64 + c*16) ^ ((n & 7) << 4))) =
            make_uint4(u0, u1, u2, u3);
    } else {
        int f = g - 16384;                      // 0..3071
        int kt = f / 384;
        int rest = f % 384;
        int n = rest >> 2, c = rest & 3;
        int k0 = kt * 32 + c * 8;
        float w[8];
        #pragma unroll
        for (int e = 0; e < 8; ++e)
            w[e] = (n < 64) ? W_so[(size_t)(k0+e)*64 + n]
                            : W_aw[(size_t)(k0+e)*32 + (n - 64)];
        *(uint4*)(imgF + (size_t)(((kt*96 + n)*4 + c)*16)) =
            make_uint4(pack2(w[0],w[1]), pack2(w[2],w[3]),
                       pack2(w[4],w[5]), pack2(w[6],w[7]));
    }
}

// ---------------------------------------------------------------------------
// K3: value GEMM via bf16 MFMA + FUSED src_t transpose emission.
// value[m][n] = sum_c src0[c][m]*W_ray[c][n] (+cam epilogue in f32).
// BM=64 x BN=256, BK=32, 4 waves. A reg-staged (f32->bf16) into XOR-swizzled
// LDS; B is a linear copy of the pre-swizzled image. Double-buffered.
// Each K-tile's As (a [64 pix][32 ch] bf16 tile of src0) is ALSO written out
// to src_t (V,HW,C bf16) -- this replaces the former k_transpose kernel and
// saves its full 157 MB src0 re-read. 4 consecutive lanes write one full
// 64B line (one pixel-row of 32 bf16).
// ---------------------------------------------------------------------------
__global__ __launch_bounds__(256, 3) void k_value(
    const float* __restrict__ src0, const float* __restrict__ cam,
    const float* __restrict__ W_ray, const float* __restrict__ b_ray,
    const unsigned char* __restrict__ imgB,
    unsigned short* __restrict__ value,
    unsigned short* __restrict__ srcT)
{
    __shared__ __align__(16) char As[2][4096];    // 64 rows x 64B (32 bf16)
    __shared__ __align__(16) char Bs[2][16384];   // 256 rows x 64B

    int t = threadIdx.x;
    int wid = t >> 6, lane = t & 63;
    int mtile = blockIdx.x;                 // 0..2399 (mtile*64 = v*HW_+pl0)
    int v   = mtile / 480;
    int pl0 = (mtile % 480) * 64;
    const float* A = src0 + (size_t)v * C_ * HW_;

    int sm = t & 63, skg = t >> 6;          // A staging: row sm, chunk skg
    const float* aptr = A + (size_t)(skg*8)*HW_ + pl0 + sm;
    const uint4* bptr = (const uint4*)imgB + t*4;   // 64B per thread per tile

    int tp  = t >> 2, tc = t & 3;           // src_t writeout: pixel tp, chunk tc

    f32x4 acc[4][4] = {};
    float ar[8]; uint4 br[4];

    // prologue: tile 0
    #pragma unroll
    for (int j = 0; j < 8; ++j) ar[j] = aptr[(size_t)j*HW_];
    #pragma unroll
    for (int j = 0; j < 4; ++j) br[j] = bptr[j];
    {
        uint4 w; w.x=pack2(ar[0],ar[1]); w.y=pack2(ar[2],ar[3]);
                 w.z=pack2(ar[4],ar[5]); w.w=pack2(ar[6],ar[7]);
        *(uint4*)(As[0] + ((sm*64 + skg*16) ^ ((sm & 7) << 4))) = w;
        #pragma unroll
        for (int j = 0; j < 4; ++j) *(uint4*)(Bs[0] + t*64 + j*16) = br[j];
    }
    __syncthreads();

    int nb = wid * 64;
    for (int kt = 0; kt < 8; ++kt) {
        int cur = kt & 1;
        if (kt < 7) {                       // issue next-tile loads early
            const float* ap = aptr + (size_t)((kt+1)*32)*HW_;
            #pragma unroll
            for (int j = 0; j < 8; ++j) ar[j] = ap[(size_t)j*HW_];
            const uint4* bp = bptr + (kt+1)*1024;
            #pragma unroll
            for (int j = 0; j < 4; ++j) br[j] = bp[j];
        }
        bf16x8 af[4], bf[4];
        #pragma unroll
        for (int i = 0; i < 4; ++i) {
            int m = i*16 + (lane & 15);
            af[i] = *(const bf16x8*)(As[cur] + ((m*64 + (lane>>4)*16) ^ ((m & 7) << 4)));
        }
        #pragma unroll
        for (int j = 0; j < 4; ++j) {
            int n = nb + j*16 + (lane & 15);
            bf[j] = *(const bf16x8*)(Bs[cur] + ((n*64 + (lane>>4)*16) ^ ((n & 7) << 4)));
        }
        // fused transpose emission: write this K-tile's bf16 src tile to src_t
        {
            uint4 row = *(const uint4*)(As[cur] + ((tp*64 + tc*16) ^ ((tp & 7) << 4)));
            *(uint4*)(srcT + ((size_t)(mtile*64 + tp))*C_ + kt*32 + tc*8) = row;
        }
        #pragma unroll
        for (int i = 0; i < 4; ++i)
            #pragma unroll
            for (int j = 0; j < 4; ++j)
                acc[i][j] = __builtin_amdgcn_mfma_f32_16x16x32_bf16(
                                af[i], bf[j], acc[i][j], 0, 0, 0);
        if (kt < 7) {                       // write-late (hidden under MFMA)
            uint4 w; w.x=pack2(ar[0],ar[1]); w.y=pack2(ar[2],ar[3]);
                     w.z=pack2(ar[4],ar[5]); w.w=pack2(ar[6],ar[7]);
            *(uint4*)(As[cur^1] + ((sm*64 + skg*16) ^ ((sm & 7) << 4))) = w;
            #pragma unroll
            for (int j = 0; j < 4; ++j) *(uint4*)(Bs[cur^1] + t*64 + j*16) = br[j];
        }
        __syncthreads();
    }

    // epilogue: bias + camera-ray rows (f32) -> bf16 store
    float wr0[4], wr1[4], wr2[4], bb[4];
    #pragma unroll
    for (int j = 0; j < 4; ++j) {
        int col = nb + j*16 + (lane & 15);
        wr0[j] = W_ray[(size_t)256*C_ + col];
        wr1[j] = W_ray[(size_t)257*C_ + col];
        wr2[j] = W_ray[(size_t)258*C_ + col];
        bb[j]  = b_ray[col];
    }
    #pragma unroll
    for (int i = 0; i < 4; ++i) {
        #pragma unroll
        for (int r = 0; r < 4; ++r) {
            int ml = i*16 + (lane>>4)*4 + r;
            int pix = pl0 + ml;
            const float* cp = cam + ((size_t)v*HW_ + pix)*3;
            float c0v = cp[0], c1v = cp[1], c2v = cp[2];
            size_t rowbase = ((size_t)mtile*64 + ml) * C_;
            #pragma unroll
            for (int j = 0; j < 4; ++j) {
                float o = acc[i][j][r] + bb[j]
                        + c0v*wr0[j] + c1v*wr1[j] + c2v*wr2[j];
                value[rowbase + nb + j*16 + (lane & 15)] = (unsigned short)f2b(o);
            }
        }
    }
}

// ---------------------------------------------------------------------------
// K2: fused ref_feat gather (bf16 src_t) + so/aw projections (MFMA) + softmax.
// ---------------------------------------------------------------------------
__global__ __launch_bounds__(256) void k_feat(
    const float* __restrict__ query, const float* __restrict__ refp,
    const unsigned short* __restrict__ srcT,
    const unsigned char* __restrict__ imgF,
    const float* __restrict__ b_so, const float* __restrict__ b_aw,
    float2* __restrict__ coords, float* __restrict__ aw_out)
{
    __shared__ __align__(16) char feat_b[8][2048];   // bf16 A-frag image, 16KB
    __shared__ float so_s[32][66];
    __shared__ float aw_s[32][34];

    int t  = threadIdx.x;
    int wid = t >> 6, lane = t & 63;
    int v  = blockIdx.x >> 7;
    int q0 = (blockIdx.x & 127) << 5;

    // ---- phase A: bilinear ref_feat + query -> feat_b (bf16 fragments) ----
    {
        int ql = t >> 3, sub = t & 7;   // 8 threads per query; sub = K-tile
        int q = q0 + ql;
        float rx = refp[((size_t)v*LQ + q)*2 + 0];
        float ry = refp[((size_t)v*LQ + q)*2 + 1];
        float gx = fminf(fmaxf(rx*2.f - 1.f, -1.1f), 1.1f);
        float gy = fminf(fmaxf(ry*2.f - 1.f, -1.1f), 1.1f);
        float x = (gx + 1.f) * (W_ * 0.5f) - 0.5f;
        float y = (gy + 1.f) * (H_ * 0.5f) - 0.5f;
        float xf = floorf(x), yf = floorf(y);
        int x0 = (int)xf, y0 = (int)yf;
        float dx = x - xf, dy = y - yf;
        float wgt[4] = {(1.f-dx)*(1.f-dy), dx*(1.f-dy), (1.f-dx)*dy, dx*dy};
        int xs[4] = {x0, x0+1, x0,   x0+1};
        int ys[4] = {y0, y0,   y0+1, y0+1};

        float accv[32];
        const float* qr = query + ((size_t)v*LQ + q)*C_ + sub*32;
        #pragma unroll
        for (int w2 = 0; w2 < 8; ++w2) {
            float4 qv = *(const float4*)(qr + w2*4);
            accv[w2*4+0]=qv.x; accv[w2*4+1]=qv.y; accv[w2*4+2]=qv.z; accv[w2*4+3]=qv.w;
        }
        #pragma unroll
        for (int cn = 0; cn < 4; ++cn) {
            int xi = xs[cn], yi = ys[cn];
            if (xi >= 0 && xi < W_ && yi >= 0 && yi < H_) {
                float wq = wgt[cn];
                const uint4* cr = (const uint4*)(srcT +
                    ((size_t)v*HW_ + (size_t)yi*W_ + xi)*C_ + sub*32);
                #pragma unroll
                for (int w2 = 0; w2 < 4; ++w2) {
                    uint4 uv = cr[w2];
                    unsigned uu[4] = {uv.x, uv.y, uv.z, uv.w};
                    #pragma unroll
                    for (int p2 = 0; p2 < 4; ++p2) {
                        accv[w2*8 + p2*2 + 0] += wq * __uint_as_float(uu[p2] << 16);
                        accv[w2*8 + p2*2 + 1] += wq * __uint_as_float(uu[p2] & 0xffff0000u);
                    }
                }
            }
        }
        // write one A-fragment row-tile: row ql, K-tile sub, chunks c2=0..3
        #pragma unroll
        for (int c2 = 0; c2 < 4; ++c2) {
            uint4 w;
            w.x = pack2(accv[c2*8+0], accv[c2*8+1]);
            w.y = pack2(accv[c2*8+2], accv[c2*8+3]);
            w.z = pack2(accv[c2*8+4], accv[c2*8+5]);
            w.w = pack2(accv[c2*8+6], accv[c2*8+7]);
            *(uint4*)(feat_b[sub] + ((ql*64 + c2*16) ^ ((ql & 7) << 4))) = w;
        }
    }
    __syncthreads();

    // ---- phase B: so/aw projections via MFMA (12 tiles, 3 per wave) ----
    #pragma unroll
    for (int jj = 0; jj < 3; ++jj) {
        int j  = wid*3 + jj;
        int mi = j / 6, ni = j % 6;
        f32x4 acc = {};
        #pragma unroll
        for (int kt = 0; kt < 8; ++kt) {
            int row = mi*16 + (lane & 15);
            bf16x8 afr = *(const bf16x8*)(feat_b[kt] +
                          ((row*64 + (lane>>4)*16) ^ ((row & 7) << 4)));
            bf16x8 bfr = *(const bf16x8*)(imgF +
                          (size_t)(((kt*96 + ni*16 + (lane & 15))*4 + (lane>>4))*16));
            acc = __builtin_amdgcn_mfma_f32_16x16x32_bf16(afr, bfr, acc, 0, 0, 0);
        }
        int col = ni*16 + (lane & 15);
        float bias = (col < 64) ? b_so[col] : b_aw[col - 64];
        #pragma unroll
        for (int r = 0; r < 4; ++r) {
            int row = mi*16 + (lane>>4)*4 + r;
            float vv = acc[r] + bias;
            if (col < 64) so_s[row][col] = vv;
            else          aw_s[row][col - 64] = vv;
        }
    }
    __syncthreads();

    // ---- phase C: softmax over P=4 per head + emit coords ----
    {
        int jq = t >> 3, h = t & 7;
        int qq = q0 + jq;
        float rx = refp[((size_t)v*LQ + qq)*2 + 0];
        float ry = refp[((size_t)v*LQ + qq)*2 + 1];
        float sc[4], m = -1e30f;
        #pragma unroll
        for (int p = 0; p < 4; ++p) { sc[p] = aw_s[jq][h*4+p]; m = fmaxf(m, sc[p]); }
        float den = 0.f;
        #pragma unroll
        for (int p = 0; p < 4; ++p) { sc[p] = __expf(sc[p]-m); den += sc[p]; }
        float inv = 1.f/den;
        size_t base = ((size_t)v*LQ + qq)*(NH*NP) + h*NP;
        #pragma unroll
        for (int p = 0; p < 4; ++p) {
            aw_out[base + p] = sc[p]*inv;
            float sx = so_s[jq][h*8 + p*2 + 0];
            float sy = so_s[jq][h*8 + p*2 + 1];
            coords[base + p] = make_float2(rx*W_ + sx - 0.5f, ry*H_ + sy - 0.5f);
        }
    }
}

// ---------------------------------------------------------------------------
// K4: deformable sampling from bf16 value; weighted sum over P; bf16 attn out.
// ---------------------------------------------------------------------------
__global__ __launch_bounds__(256) void k_sample(
    const unsigned short* __restrict__ value, const float2* __restrict__ coords,
    const float* __restrict__ aw, unsigned short* __restrict__ attnb)
{
    int t = threadIdx.x;
    int h = t >> 5;      // 0..7
    int d = t & 31;      // 0..31
    int vq0 = blockIdx.x * 4;
    #pragma unroll
    for (int ql = 0; ql < 4; ++ql) {
        int vq = vq0 + ql;
        int v = vq >> 12;
        size_t cbase = (size_t)vq * (NH*NP) + h*NP;
        const unsigned short* vb = value + (size_t)v*HW_*C_ + h*DH + d;
        float o = 0.f;
        #pragma unroll
        for (int p = 0; p < 4; ++p) {
            float2 cc = coords[cbase + p];
            float a   = aw[cbase + p];
            float xf = floorf(cc.x), yf = floorf(cc.y);
            int x0 = (int)xf, y0 = (int)yf;
            float dx = cc.x - xf, dy = cc.y - yf;
            bool xv0 = (x0 >= 0) & (x0 < W_);
            bool xv1 = (x0 >= -1) & (x0 < W_-1);
            bool yv0 = (y0 >= 0) & (y0 < H_);
            bool yv1 = (y0 >= -1) & (y0 < H_-1);
            float s = 0.f;
            if (yv0 & xv0) s += (1.f-dx)*(1.f-dy) *
                __uint_as_float((unsigned)vb[(size_t)(y0*W_ + x0)*C_] << 16);
            if (yv0 & xv1) s += dx*(1.f-dy) *
                __uint_as_float((unsigned)vb[(size_t)(y0*W_ + x0+1)*C_] << 16);
            if (yv1 & xv0) s += (1.f-dx)*dy *
                __uint_as_float((unsigned)vb[(size_t)((y0+1)*W_ + x0)*C_] << 16);
            if (yv1 & xv1) s += dx*dy *
                __uint_as_float((unsigned)vb[(size_t)((y0+1)*W_ + x0+1)*C_] << 16);
            o += a * s;
        }
        attnb[(size_t)vq*C_ + h*DH + d] = (unsigned short)f2b(o);
    }
}

// ---------------------------------------------------------------------------
// K5: out = attn(bf16) @ W_out + b_out, f32 result. Same MFMA structure.
// ---------------------------------------------------------------------------
__global__ __launch_bounds__(256, 3) void k_out(
    const unsigned short* __restrict__ attnb, const unsigned char* __restrict__ imgB,
    const float* __restrict__ b_out, float* __restrict__ outp)
{
    __shared__ __align__(16) char As[2][4096];
    __shared__ __align__(16) char Bs[2][16384];

    int t = threadIdx.x;
    int wid = t >> 6, lane = t & 63;
    int m0 = blockIdx.x * 64;

    int sm = t >> 2, skg = t & 3;           // A staging: row sm, chunk skg
    const uint4* bptr = (const uint4*)imgB + t*4;

    f32x4 acc[4][4] = {};
    uint4 ar, br[4];

    ar = *(const uint4*)(attnb + (size_t)(m0+sm)*C_ + skg*8);
    #pragma unroll
    for (int j = 0; j < 4; ++j) br[j] = bptr[j];
    *(uint4*)(As[0] + ((sm*64 + skg*16) ^ ((sm & 7) << 4))) = ar;
    #pragma unroll
    for (int j = 0; j < 4; ++j) *(uint4*)(Bs[0] + t*64 + j*16) = br[j];
    __syncthreads();

    int nb = wid * 64;
    for (int kt = 0; kt < 8; ++kt) {
        int cur = kt & 1;
        if (kt < 7) {
            ar = *(const uint4*)(attnb + (size_t)(m0+sm)*C_ + (kt+1)*32 + skg*8);
            const uint4* bp = bptr + (kt+1)*1024;
            #pragma unroll
            for (int j = 0; j < 4; ++j) br[j] = bp[j];
        }
        bf16x8 af[4], bf[4];
        #pragma unroll
        for (int i = 0; i < 4; ++i) {
            int m = i*16 + (lane & 15);
            af[i] = *(const bf16x8*)(As[cur] + ((m*64 + (lane>>4)*16) ^ ((m & 7) << 4)));
        }
        #pragma unroll
        for (int j = 0; j < 4; ++j) {
            int n = nb + j*16 + (lane & 15);
            bf[j] = *(const bf16x8*)(Bs[cur] + ((n*64 + (lane>>4)*16) ^ ((n & 7) << 4)));
        }
        #pragma unroll
        for (int i = 0; i < 4; ++i)
            #pragma unroll
            for (int j = 0; j < 4; ++j)
                acc[i][j] = __builtin_amdgcn_mfma_f32_16x16x32_bf16(
                                af[i], bf[j], acc[i][j], 0, 0, 0);
        if (kt < 7) {
            *(uint4*)(As[cur^1] + ((sm*64 + skg*16) ^ ((sm & 7) << 4))) = ar;
            #pragma unroll
            for (int j = 0; j < 4; ++j) *(uint4*)(Bs[cur^1] + t*64 + j*16) = br[j];
        }
        __syncthreads();
    }

    float bb[4];
    #pragma unroll
    for (int j = 0; j < 4; ++j) bb[j] = b_out[nb + j*16 + (lane & 15)];
    #pragma unroll
    for (int i = 0; i < 4; ++i) {
        #pragma unroll
        for (int r = 0; r < 4; ++r) {
            int ml = i*16 + (lane>>4)*4 + r;
            size_t rowbase = (size_t)(m0 + ml) * C_;
            #pragma unroll
            for (int j = 0; j < 4; ++j)
                outp[rowbase + nb + j*16 + (lane & 15)] = acc[i][j][r] + bb[j];
        }
    }
}

// ---------------------------------------------------------------------------
extern "C" void kernel_launch(void* const* d_in, const int* in_sizes, int n_in,
                              void* d_out, int out_size, void* d_ws, size_t ws_size,
                              hipStream_t stream)
{
    (void)in_sizes; (void)n_in; (void)out_size; (void)ws_size;
    const float* query = (const float*)d_in[0];
    const float* refp  = (const float*)d_in[1];
    const float* src0  = (const float*)d_in[2];
    const float* cam   = (const float*)d_in[3];
    const float* W_ray = (const float*)d_in[6];
    const float* b_ray = (const float*)d_in[7];
    const float* W_so  = (const float*)d_in[8];
    const float* b_so  = (const float*)d_in[9];
    const float* W_aw  = (const float*)d_in[10];
    const float* b_aw  = (const float*)d_in[11];
    const float* W_out = (const float*)d_in[12];
    const float* b_out = (const float*)d_in[13];
    float* out = (float*)d_out;

    // ws layout (bytes):
    //   value  @ 0           : 78,643,200  (bf16)
    //   srcT   @ 78,643,200  : 78,643,200  (bf16, emitted by k_value)
    //   imgR   @ 157,286,400 :    131,072
    //   imgO   @ 157,417,472 :    131,072
    //   imgF   @ 157,548,544 :     49,152
    //   coords @ 157,597,696 :  5,242,880
    //   aw     @ 162,840,576 :  2,621,440
    //   attnb  @ 165,462,016 : 10,485,760   -> total 175,947,776
    char* ws = (char*)d_ws;
    unsigned short* value = (unsigned short*)(ws);
    unsigned short* srcT  = (unsigned short*)(ws + 78643200);
    unsigned char*  imgR  = (unsigned char*)(ws + 157286400);
    unsigned char*  imgO  = (unsigned char*)(ws + 157417472);
    unsigned char*  imgF  = (unsigned char*)(ws + 157548544);
    float2*         coords= (float2*)(ws + 157597696);
    float*          awbuf = (float*)(ws + 162840576);
    unsigned short* attnb = (unsigned short*)(ws + 165462016);

    k_prep<<<dim3(76), 256, 0, stream>>>(W_ray, W_out, W_so, W_aw, imgR, imgO, imgF);
    // k_value now also emits srcT (fused transpose) -> k_transpose deleted
    k_value<<<dim3((V_*HW_)/64), 256, 0, stream>>>(src0, cam, W_ray, b_ray, imgR,
                                                   value, srcT);
    k_feat<<<dim3(V_*(LQ/32)), 256, 0, stream>>>(query, refp, srcT, imgF,
                                                 b_so, b_aw, coords, awbuf);
    k_sample<<<dim3(V_*LQ/4), 256, 0, stream>>>(value, coords, awbuf, attnb);
    k_out<<<dim3(V_*LQ/64), 256, 0, stream>>>(attnb, imgO, b_out, out);
}